// Round 1
// baseline (240.185 us; speedup 1.0000x reference)
//
#include <hip/hip_runtime.h>

static constexpr int B = 4;
static constexpr int N = 8192;
static constexpr int H = 8;
static constexpr int BH = B * H;   // 32
#define EPSF 1e-6f

typedef _Float16 f16;
typedef _Float16 f16x8 __attribute__((ext_vector_type(8)));
typedef float f32x4 __attribute__((ext_vector_type(4)));

__device__ __forceinline__ float featmap(float x) {
    return x > 0.0f ? (x + 1.0f) : __expf(x);   // elu(x)+1
}

union H8 { f16x8 v; unsigned long long u[2]; };
__device__ __forceinline__ f16x8 lds_load8(const f16* p) {
    H8 r;
    r.u[0] = *(const unsigned long long*)(p);
    r.u[1] = *(const unsigned long long*)(p + 4);
    return r.v;
}
__device__ __forceinline__ unsigned pack2(float a, float b) {
    union { f16 h[2]; unsigned u; } x;
    x.h[0] = (f16)a; x.h[1] = (f16)b;
    return x.u;
}
__device__ __forceinline__ unsigned long long pack4(float a, float b, float c, float d) {
    union { f16 h[4]; unsigned long long u; } x;
    x.h[0] = (f16)a; x.h[1] = (f16)b; x.h[2] = (f16)c; x.h[3] = (f16)d;
    return x.u;
}

// ---------------------------------------------------------------------------
// Pass 1 (MFMA): KV[bh][m][d] = sum_n V[n][m]*fK[n][d];  Ksum[bh][d] += sum_n fK[n][d]
// grid (BH, S1), block 256 (4 waves). Each block: 128 rows = 4 K-steps of 32.
// S1=64 -> 2048 blocks = 8 blocks/CU (LDS 19456B x 8 = 155KB fits 160KB).
// Occupancy was the limiter at S1=16 (2 blocks/CU, 18.8%).
// ---------------------------------------------------------------------------
static constexpr int S1 = 64;
static constexpr int ROWS1 = N / S1;       // 128
static constexpr int NSTEPS1 = ROWS1 / 32; // 4

__global__ __launch_bounds__(256, 2) void kv_pass(
    const float* __restrict__ keys,
    const float* __restrict__ values,
    const float* __restrict__ mask,
    float* __restrict__ kv,     // [BH][64][64] (m,d) fp32, pre-zeroed
    float* __restrict__ ksum)   // [BH][64] fp32, pre-zeroed
{
    const int bh = blockIdx.x, b = bh >> 3, h = bh & 7;
    const int t = threadIdx.x;
    const int wave = t >> 6, lane = t & 63;
    const int p = t >> 4;          // 0..15: row-pair within K-step
    const int c = t & 15;          // float4 column (d/m group)
    const int quad = lane >> 4;    // 0..3
    const int l15 = lane & 15;
    const int n0 = blockIdx.y * ROWS1;

    __shared__ f16 KT[2][64][36];  // [buf][d][n] pitch 72B: frag reads conflict-free
    __shared__ f16 VT[2][64][36];  // [buf][m][n]
    __shared__ float Ksw[4][64];

    const float* mrow = mask + (size_t)b * N;

    // prefetch step 0
    int n = n0 + 2 * p;
    size_t g0 = ((size_t)((b * N + n) * H + h)) * 64 + c * 4;
    size_t g1 = g0 + (size_t)H * 64;
    float4 kq0 = *(const float4*)(keys + g0);
    float4 kq1 = *(const float4*)(keys + g1);
    float4 vq0 = *(const float4*)(values + g0);
    float4 vq1 = *(const float4*)(values + g1);
    float mk0 = mrow[n], mk1 = mrow[n + 1];

    f32x4 acc[4];
    #pragma unroll
    for (int i = 0; i < 4; ++i) acc[i] = (f32x4){0.f, 0.f, 0.f, 0.f};
    float ksacc[4] = {0.f, 0.f, 0.f, 0.f};

    for (int s = 0; s < NSTEPS1; ++s) {
        const int buf = s & 1;
        // featmap + mask in fp32, accumulate ksum, write fp16 transposed tiles
        const float fk0[4] = {featmap(kq0.x) * mk0, featmap(kq0.y) * mk0,
                              featmap(kq0.z) * mk0, featmap(kq0.w) * mk0};
        const float fk1[4] = {featmap(kq1.x) * mk1, featmap(kq1.y) * mk1,
                              featmap(kq1.z) * mk1, featmap(kq1.w) * mk1};
        const float fv0[4] = {vq0.x, vq0.y, vq0.z, vq0.w};
        const float fv1[4] = {vq1.x, vq1.y, vq1.z, vq1.w};
        #pragma unroll
        for (int dd = 0; dd < 4; ++dd) {
            ksacc[dd] += fk0[dd] + fk1[dd];
            *(unsigned*)&KT[buf][c * 4 + dd][2 * p] = pack2(fk0[dd], fk1[dd]);
            *(unsigned*)&VT[buf][c * 4 + dd][2 * p] = pack2(fv0[dd], fv1[dd]);
        }
        // prefetch next K-step (global only; no LDS dependency)
        if (s + 1 < NSTEPS1) {
            const int nn = n0 + (s + 1) * 32 + 2 * p;
            const size_t h0 = ((size_t)((b * N + nn) * H + h)) * 64 + c * 4;
            const size_t h1 = h0 + (size_t)H * 64;
            kq0 = *(const float4*)(keys + h0);
            kq1 = *(const float4*)(keys + h1);
            vq0 = *(const float4*)(values + h0);
            vq1 = *(const float4*)(values + h1);
            mk0 = mrow[nn]; mk1 = mrow[nn + 1];
        }
        __syncthreads();
        // fragments + MFMA: D[m][d] += A(V^T) * B(fK)
        const f16x8 afr = lds_load8(&VT[buf][wave * 16 + l15][quad * 8]);
        #pragma unroll
        for (int dt = 0; dt < 4; ++dt) {
            const f16x8 bfr = lds_load8(&KT[buf][dt * 16 + l15][quad * 8]);
            acc[dt] = __builtin_amdgcn_mfma_f32_16x16x32_f16(afr, bfr, acc[dt], 0, 0, 0);
        }
    }

    // KV output: D row = m = 16*wave + 4*quad + reg, col = d = 16*dt + l15
    float* kvb = kv + (size_t)bh * 4096;
    #pragma unroll
    for (int dt = 0; dt < 4; ++dt) {
        #pragma unroll
        for (int reg = 0; reg < 4; ++reg) {
            const int m = wave * 16 + quad * 4 + reg;
            atomicAdd(kvb + m * 64 + dt * 16 + l15, acc[dt][reg]);
        }
    }
    // Ksum: reduce over p within wave (lanes sharing c), then across waves via LDS
    #pragma unroll
    for (int dd = 0; dd < 4; ++dd) {
        float v = ksacc[dd];
        v += __shfl_xor(v, 16);
        v += __shfl_xor(v, 32);
        if (lane < 16) Ksw[wave][lane * 4 + dd] = v;
    }
    __syncthreads();
    if (t < 64) {
        atomicAdd(ksum + bh * 64 + t, Ksw[0][t] + Ksw[1][t] + Ksw[2][t] + Ksw[3][t]);
    }
}

// ---------------------------------------------------------------------------
// Pass 2 (MFMA): out[n][m] = (sum_d fQ[n][d]*KV[m][d]) / (sum_d fQ[n][d]*Ksum[d] + eps)
// grid (BH, S2), block 256. Block covers 128 n-rows; wave w rows [32w,32w+32).
// S2=64 -> 2048 blocks; LDS 26.4KB -> 6 blocks/CU (was 44KB -> 3 blocks/CU).
// B-frags (KV, natural layout) + z-tile (Ksum in col 0) held in registers.
// ---------------------------------------------------------------------------
static constexpr int S2 = 64;
static constexpr int ROWS2 = N / S2;   // 128

__global__ __launch_bounds__(256, 2) void out_pass(
    const float* __restrict__ queries,
    const float* __restrict__ kv,
    const float* __restrict__ ksum,
    float* __restrict__ out)
{
    const int bh = blockIdx.x, b = bh >> 3, h = bh & 7;
    const int t = threadIdx.x;
    const int wave = t >> 6, lane = t & 63;
    const int quad = lane >> 4;
    const int l15 = lane & 15;
    const int n0 = blockIdx.y * ROWS2;

    __shared__ f16 Qsh[ROWS2][68];   // [n][d] pitch 136B
    __shared__ f16 KVh[64][68];      // [m][d]
    __shared__ float Ksh[64];

    // stage KV (fp32 ws -> fp16 LDS, natural [m][d] layout)
    #pragma unroll
    for (int l = 0; l < 4; ++l) {
        const int idx = t + l * 256;
        const int m = idx >> 4, cc = idx & 15;
        const float4 v = *(const float4*)(kv + (size_t)bh * 4096 + m * 64 + cc * 4);
        *(unsigned long long*)&KVh[m][cc * 4] = pack4(v.x, v.y, v.z, v.w);
    }
    if (t < 64) Ksh[t] = ksum[bh * 64 + t];

    // stage fQ rows
    #pragma unroll
    for (int l = 0; l < ROWS2 * 16 / 256; ++l) {   // 8
        const int idx = t + l * 256;
        const int r = idx >> 4, cc = idx & 15;
        const int nn = n0 + r;
        const float4 q = *(const float4*)(queries + ((size_t)((b * N + nn) * H + h)) * 64 + cc * 4);
        *(unsigned long long*)&Qsh[r][cc * 4] =
            pack4(featmap(q.x), featmap(q.y), featmap(q.z), featmap(q.w));
    }
    __syncthreads();

    // B-frags in registers: KV tiles [mt][kstep] + z-tile (Ksum in col 0)
    f16x8 bfr[4][2];
    #pragma unroll
    for (int mt = 0; mt < 4; ++mt)
        #pragma unroll
        for (int ks = 0; ks < 2; ++ks)
            bfr[mt][ks] = lds_load8(&KVh[mt * 16 + l15][ks * 32 + quad * 8]);
    f16x8 bz[2];
    #pragma unroll
    for (int ks = 0; ks < 2; ++ks) {
        #pragma unroll
        for (int j = 0; j < 8; ++j) {
            const float kval = Ksh[ks * 32 + quad * 8 + j];
            bz[ks][j] = (l15 == 0) ? (f16)kval : (f16)0.f;
        }
    }

    #pragma unroll
    for (int nt = 0; nt < 2; ++nt) {
        const int r0 = wave * 32 + nt * 16;
        f32x4 acc[4];
        #pragma unroll
        for (int i = 0; i < 4; ++i) acc[i] = (f32x4){0.f, 0.f, 0.f, 0.f};
        f32x4 az = (f32x4){0.f, 0.f, 0.f, 0.f};

        #pragma unroll
        for (int ks = 0; ks < 2; ++ks) {
            const f16x8 afr = lds_load8(&Qsh[r0 + l15][ks * 32 + quad * 8]);
            #pragma unroll
            for (int mt = 0; mt < 4; ++mt)
                acc[mt] = __builtin_amdgcn_mfma_f32_16x16x32_f16(afr, bfr[mt][ks], acc[mt], 0, 0, 0);
            az = __builtin_amdgcn_mfma_f32_16x16x32_f16(afr, bz[ks], az, 0, 0, 0);
        }

        // epilogue: den sits in col 0 (lane&15==0) of az; broadcast within quad
        #pragma unroll
        for (int reg = 0; reg < 4; ++reg) {
            const float den = __shfl(az[reg], lane & 48);
            const float zin = 1.0f / (den + EPSF);
            const int nn = n0 + r0 + quad * 4 + reg;
            float* op = out + ((size_t)((b * N + nn) * H + h)) * 64 + l15;
            #pragma unroll
            for (int mt = 0; mt < 4; ++mt)
                op[mt * 16] = acc[mt][reg] * zin;
        }
    }
}

extern "C" void kernel_launch(void* const* d_in, const int* in_sizes, int n_in,
                              void* d_out, int out_size, void* d_ws, size_t ws_size,
                              hipStream_t stream)
{
    const float* q    = (const float*)d_in[0];
    const float* k    = (const float*)d_in[1];
    const float* v    = (const float*)d_in[2];
    const float* mask = (const float*)d_in[3];
    float* out = (float*)d_out;

    float* kv = (float*)d_ws;                  // [BH][64][64]
    float* ks = kv + (size_t)BH * 64 * 64;     // [BH][64]

    hipMemsetAsync(d_ws, 0, (size_t)(BH * 64 * 64 + BH * 64) * sizeof(float), stream);
    kv_pass<<<dim3(BH, S1), 256, 0, stream>>>(k, v, mask, kv, ks);
    out_pass<<<dim3(BH, S2), 256, 0, stream>>>(q, kv, ks, out);
}

// Round 3
// 239.668 us; speedup vs baseline: 1.0022x; 1.0022x over previous
//
#include <hip/hip_runtime.h>

static constexpr int B = 4;
static constexpr int N = 8192;
static constexpr int H = 8;
static constexpr int BH = B * H;   // 32
#define EPSF 1e-6f

typedef _Float16 f16;
typedef _Float16 f16x8 __attribute__((ext_vector_type(8)));
typedef float f32x4 __attribute__((ext_vector_type(4)));

__device__ __forceinline__ float featmap(float x) {
    return x > 0.0f ? (x + 1.0f) : __expf(x);   // elu(x)+1
}

union H8 { f16x8 v; unsigned long long u[2]; };
__device__ __forceinline__ f16x8 lds_load8(const f16* p) {
    H8 r;
    r.u[0] = *(const unsigned long long*)(p);
    r.u[1] = *(const unsigned long long*)(p + 4);
    return r.v;
}
__device__ __forceinline__ unsigned pack2(float a, float b) {
    union { f16 h[2]; unsigned u; } x;
    x.h[0] = (f16)a; x.h[1] = (f16)b;
    return x.u;
}
__device__ __forceinline__ unsigned long long pack4(float a, float b, float c, float d) {
    union { f16 h[4]; unsigned long long u; } x;
    x.h[0] = (f16)a; x.h[1] = (f16)b; x.h[2] = (f16)c; x.h[3] = (f16)d;
    return x.u;
}

// ---------------------------------------------------------------------------
// Pass 1 (MFMA): KV[bh][m][d] = sum_n V[n][m]*fK[n][d];  Ksum[bh][d] = sum_n fK[n][d]
// grid (BH, S1), block 256 (4 waves). S1=32 -> 1024 blocks = 4 blocks/CU,
// 8 K-steps of 32 rows per block.
// ATOMIC=false: each block plain-stores its partial tile to a private ws
// slice (race-free: waves own disjoint m-strips); reduce_pass sums the
// partials. Removes all atomics AND the memset dispatch.
// ---------------------------------------------------------------------------
static constexpr int S1 = 32;
static constexpr int ROWS1 = N / S1;       // 256
static constexpr int NSTEPS1 = ROWS1 / 32; // 8

template<bool ATOMIC>
__global__ __launch_bounds__(256, 4) void kv_pass(
    const float* __restrict__ keys,
    const float* __restrict__ values,
    const float* __restrict__ mask,
    float* __restrict__ kv,     // ATOMIC: [BH][64][64] pre-zeroed; else [S1][BH][64][64]
    float* __restrict__ ksum)   // ATOMIC: [BH][64] pre-zeroed;     else [S1][BH][64]
{
    const int bh = blockIdx.x, b = bh >> 3, h = bh & 7;
    const int t = threadIdx.x;
    const int wave = t >> 6, lane = t & 63;
    const int p = t >> 4;          // 0..15: row-pair within K-step
    const int c = t & 15;          // float4 column (d/m group)
    const int quad = lane >> 4;    // 0..3
    const int l15 = lane & 15;
    const int n0 = blockIdx.y * ROWS1;

    __shared__ f16 KT[2][64][36];  // [buf][d][n] pitch 72B
    __shared__ f16 VT[2][64][36];  // [buf][m][n]
    __shared__ float Ksw[4][64];

    const float* mrow = mask + (size_t)b * N;

    // prefetch step 0
    int n = n0 + 2 * p;
    size_t g0 = ((size_t)((b * N + n) * H + h)) * 64 + c * 4;
    size_t g1 = g0 + (size_t)H * 64;
    float4 kq0 = *(const float4*)(keys + g0);
    float4 kq1 = *(const float4*)(keys + g1);
    float4 vq0 = *(const float4*)(values + g0);
    float4 vq1 = *(const float4*)(values + g1);
    float mk0 = mrow[n], mk1 = mrow[n + 1];

    f32x4 acc[4];
    #pragma unroll
    for (int i = 0; i < 4; ++i) acc[i] = (f32x4){0.f, 0.f, 0.f, 0.f};
    float ksacc[4] = {0.f, 0.f, 0.f, 0.f};

    for (int s = 0; s < NSTEPS1; ++s) {
        const int buf = s & 1;
        const float fk0[4] = {featmap(kq0.x) * mk0, featmap(kq0.y) * mk0,
                              featmap(kq0.z) * mk0, featmap(kq0.w) * mk0};
        const float fk1[4] = {featmap(kq1.x) * mk1, featmap(kq1.y) * mk1,
                              featmap(kq1.z) * mk1, featmap(kq1.w) * mk1};
        const float fv0[4] = {vq0.x, vq0.y, vq0.z, vq0.w};
        const float fv1[4] = {vq1.x, vq1.y, vq1.z, vq1.w};
        #pragma unroll
        for (int dd = 0; dd < 4; ++dd) {
            ksacc[dd] += fk0[dd] + fk1[dd];
            *(unsigned*)&KT[buf][c * 4 + dd][2 * p] = pack2(fk0[dd], fk1[dd]);
            *(unsigned*)&VT[buf][c * 4 + dd][2 * p] = pack2(fv0[dd], fv1[dd]);
        }
        if (s + 1 < NSTEPS1) {
            const int nn = n0 + (s + 1) * 32 + 2 * p;
            const size_t h0 = ((size_t)((b * N + nn) * H + h)) * 64 + c * 4;
            const size_t h1 = h0 + (size_t)H * 64;
            kq0 = *(const float4*)(keys + h0);
            kq1 = *(const float4*)(keys + h1);
            vq0 = *(const float4*)(values + h0);
            vq1 = *(const float4*)(values + h1);
            mk0 = mrow[nn]; mk1 = mrow[nn + 1];
        }
        __syncthreads();
        const f16x8 afr = lds_load8(&VT[buf][wave * 16 + l15][quad * 8]);
        #pragma unroll
        for (int dt = 0; dt < 4; ++dt) {
            const f16x8 bfr = lds_load8(&KT[buf][dt * 16 + l15][quad * 8]);
            acc[dt] = __builtin_amdgcn_mfma_f32_16x16x32_f16(afr, bfr, acc[dt], 0, 0, 0);
        }
    }

    // KV output: D row = m = 16*wave + 4*quad + reg, col = d = 16*dt + l15
    float* kvb = ATOMIC ? (kv + (size_t)bh * 4096)
                        : (kv + ((size_t)blockIdx.y * BH + bh) * 4096);
    #pragma unroll
    for (int dt = 0; dt < 4; ++dt) {
        #pragma unroll
        for (int reg = 0; reg < 4; ++reg) {
            const int m = wave * 16 + quad * 4 + reg;
            if (ATOMIC) atomicAdd(kvb + m * 64 + dt * 16 + l15, acc[dt][reg]);
            else        kvb[m * 64 + dt * 16 + l15] = acc[dt][reg];
        }
    }
    // Ksum: reduce over p within wave, then across waves via LDS
    #pragma unroll
    for (int dd = 0; dd < 4; ++dd) {
        float v = ksacc[dd];
        v += __shfl_xor(v, 16);
        v += __shfl_xor(v, 32);
        if (lane < 16) Ksw[wave][lane * 4 + dd] = v;
    }
    __syncthreads();
    if (t < 64) {
        const float s4 = Ksw[0][t] + Ksw[1][t] + Ksw[2][t] + Ksw[3][t];
        if (ATOMIC) atomicAdd(ksum + bh * 64 + t, s4);
        else        ksum[((size_t)blockIdx.y * BH + bh) * 64 + t] = s4;
    }
}

// ---------------------------------------------------------------------------
// Sum the S1 partial tiles: kv[idx] = sum_s pkv[s][idx], ksum likewise.
// ---------------------------------------------------------------------------
__global__ __launch_bounds__(256) void reduce_pass(
    const float* __restrict__ pkv, const float* __restrict__ pks,
    float* __restrict__ kv, float* __restrict__ ksum)
{
    const int idx = blockIdx.x * 256 + threadIdx.x;
    if (idx < BH * 4096) {
        float s = 0.f;
        #pragma unroll 8
        for (int j = 0; j < S1; ++j) s += pkv[(size_t)j * (BH * 4096) + idx];
        kv[idx] = s;
    } else if (idx < BH * 4096 + BH * 64) {
        const int k = idx - BH * 4096;   // < BH*64
        float s = 0.f;
        #pragma unroll 8
        for (int j = 0; j < S1; ++j) s += pks[(size_t)j * (BH * 64) + k];
        ksum[k] = s;
    }
}

// ---------------------------------------------------------------------------
// Pass 2 (MFMA): out[n][m] = (sum_d fQ[n][d]*KV[m][d]) / (sum_d fQ[n][d]*Ksum[d] + eps)
// grid (BH, S2=64), block 256. Block covers 128 n-rows; LDS 26.4KB.
// ---------------------------------------------------------------------------
static constexpr int S2 = 64;
static constexpr int ROWS2 = N / S2;   // 128

__global__ __launch_bounds__(256, 2) void out_pass(
    const float* __restrict__ queries,
    const float* __restrict__ kv,
    const float* __restrict__ ksum,
    float* __restrict__ out)
{
    const int bh = blockIdx.x, b = bh >> 3, h = bh & 7;
    const int t = threadIdx.x;
    const int wave = t >> 6, lane = t & 63;
    const int quad = lane >> 4;
    const int l15 = lane & 15;
    const int n0 = blockIdx.y * ROWS2;

    __shared__ f16 Qsh[ROWS2][68];   // [n][d] pitch 136B
    __shared__ f16 KVh[64][68];      // [m][d]
    __shared__ float Ksh[64];

    #pragma unroll
    for (int l = 0; l < 4; ++l) {
        const int idx = t + l * 256;
        const int m = idx >> 4, cc = idx & 15;
        const float4 v = *(const float4*)(kv + (size_t)bh * 4096 + m * 64 + cc * 4);
        *(unsigned long long*)&KVh[m][cc * 4] = pack4(v.x, v.y, v.z, v.w);
    }
    if (t < 64) Ksh[t] = ksum[bh * 64 + t];

    #pragma unroll
    for (int l = 0; l < ROWS2 * 16 / 256; ++l) {   // 8
        const int idx = t + l * 256;
        const int r = idx >> 4, cc = idx & 15;
        const int nn = n0 + r;
        const float4 q = *(const float4*)(queries + ((size_t)((b * N + nn) * H + h)) * 64 + cc * 4);
        *(unsigned long long*)&Qsh[r][cc * 4] =
            pack4(featmap(q.x), featmap(q.y), featmap(q.z), featmap(q.w));
    }
    __syncthreads();

    f16x8 bfr[4][2];
    #pragma unroll
    for (int mt = 0; mt < 4; ++mt)
        #pragma unroll
        for (int ks = 0; ks < 2; ++ks)
            bfr[mt][ks] = lds_load8(&KVh[mt * 16 + l15][ks * 32 + quad * 8]);
    f16x8 bz[2];
    #pragma unroll
    for (int ks = 0; ks < 2; ++ks) {
        #pragma unroll
        for (int j = 0; j < 8; ++j) {
            const float kval = Ksh[ks * 32 + quad * 8 + j];
            bz[ks][j] = (l15 == 0) ? (f16)kval : (f16)0.f;
        }
    }

    #pragma unroll
    for (int nt = 0; nt < 2; ++nt) {
        const int r0 = wave * 32 + nt * 16;
        f32x4 acc[4];
        #pragma unroll
        for (int i = 0; i < 4; ++i) acc[i] = (f32x4){0.f, 0.f, 0.f, 0.f};
        f32x4 az = (f32x4){0.f, 0.f, 0.f, 0.f};

        #pragma unroll
        for (int ks = 0; ks < 2; ++ks) {
            const f16x8 afr = lds_load8(&Qsh[r0 + l15][ks * 32 + quad * 8]);
            #pragma unroll
            for (int mt = 0; mt < 4; ++mt)
                acc[mt] = __builtin_amdgcn_mfma_f32_16x16x32_f16(afr, bfr[mt][ks], acc[mt], 0, 0, 0);
            az = __builtin_amdgcn_mfma_f32_16x16x32_f16(afr, bz[ks], az, 0, 0, 0);
        }

        #pragma unroll
        for (int reg = 0; reg < 4; ++reg) {
            const float den = __shfl(az[reg], lane & 48);
            const float zin = 1.0f / (den + EPSF);
            const int nn = n0 + r0 + quad * 4 + reg;
            float* op = out + ((size_t)((b * N + nn) * H + h)) * 64 + l15;
            #pragma unroll
            for (int mt = 0; mt < 4; ++mt)
                op[mt * 16] = acc[mt][reg] * zin;
        }
    }
}

extern "C" void kernel_launch(void* const* d_in, const int* in_sizes, int n_in,
                              void* d_out, int out_size, void* d_ws, size_t ws_size,
                              hipStream_t stream)
{
    const float* q    = (const float*)d_in[0];
    const float* k    = (const float*)d_in[1];
    const float* v    = (const float*)d_in[2];
    const float* mask = (const float*)d_in[3];
    float* out = (float*)d_out;

    const size_t PKV = (size_t)S1 * BH * 4096;   // partial KV floats
    const size_t PKS = (size_t)S1 * BH * 64;     // partial Ksum floats
    const size_t FIN = (size_t)BH * 4096 + BH * 64;
    const size_t need = (PKV + PKS + FIN) * sizeof(float);

    if (ws_size >= need) {
        // atomic-free path: partials + reduce, no memset dispatch
        float* pkv = (float*)d_ws;
        float* pks = pkv + PKV;
        float* kvf = pks + PKS;
        float* ksf = kvf + (size_t)BH * 4096;
        kv_pass<false><<<dim3(BH, S1), 256, 0, stream>>>(k, v, mask, pkv, pks);
        const int redElems = BH * 4096 + BH * 64;
        reduce_pass<<<dim3((redElems + 255) / 256), 256, 0, stream>>>(pkv, pks, kvf, ksf);
        out_pass<<<dim3(BH, S2), 256, 0, stream>>>(q, kvf, ksf, out);
    } else {
        // fallback: atomic accumulation into pre-zeroed final buffers
        float* kvf = (float*)d_ws;
        float* ksf = kvf + (size_t)BH * 4096;
        hipMemsetAsync(d_ws, 0, FIN * sizeof(float), stream);
        kv_pass<true><<<dim3(BH, S1), 256, 0, stream>>>(k, v, mask, kvf, ksf);
        out_pass<<<dim3(BH, S2), 256, 0, stream>>>(q, kvf, ksf, out);
    }
}